// Round 1
// baseline (236.160 us; speedup 1.0000x reference)
//
#include <hip/hip_runtime.h>
#include <math.h>

namespace {
constexpr int kB = 64;
constexpr int kT = 1024;
constexpr int kK = 512;
constexpr int kP = 32;            // prefetch depth; divides kT
constexpr float kDT = 0.001f;
}

// One thread per (b,k) chain. k is the fastest-varying thread index so each
// wave's 64 lanes touch 64 consecutive floats (256 B coalesced) per step.
// A 32-deep register circular buffer keeps 32 loads in flight per wave
// (32 x 256 B x 2 waves/CU = 16 KiB in flight/CU >= ~9.2 KiB needed to
// sustain 6.3 TB/s at ~900 cyc HBM latency).
__global__ __launch_bounds__(64, 1) void alpha_scan(
    const float* __restrict__ in,
    const float* __restrict__ init_level,
    const float* __restrict__ tau,
    float* __restrict__ out)
{
    const int gid = blockIdx.x * blockDim.x + threadIdx.x;   // 0..32767
    const int k = gid & (kK - 1);
    const int b = gid >> 9;                                   // /512

    // Per-feature coefficients (match reference arithmetic).
    const float tc      = fmaxf(tau[k], 1e-8f);
    const float dt_tau  = kDT / tc;
    const float dt_tau2 = dt_tau / tc;
    const float e       = expf(-dt_tau);

    const float a00 = e * (1.0f - dt_tau);
    const float a01 = e * (-dt_tau2);
    const float a10 = e * kDT;
    const float a11 = e * (1.0f + dt_tau);
    const float b0  = e * dt_tau2;
    const float b1  = 1.0f - e * (1.0f + dt_tau);

    float x0 = 0.0f;
    float x1 = init_level[k];

    const float* __restrict__ pin = in  + (size_t)b * kT * kK + k;
    float* __restrict__ pout      = out + (size_t)b * kT * kK + k;

    // Prologue: fill the prefetch buffer with u[0..P-1].
    float buf[kP];
    #pragma unroll
    for (int i = 0; i < kP; ++i) buf[i] = pin[(size_t)i * kK];

    // Main loop: consume buf[i] (t = tb+i), prefetch t = tb+P+i.
    for (int tb = 0; tb < kT - kP; tb += kP) {
        const float* __restrict__ pld = pin  + (size_t)(tb + kP) * kK;
        float* __restrict__ pst       = pout + (size_t)tb * kK;
        #pragma unroll
        for (int i = 0; i < kP; ++i) {
            const float u = buf[i];
            buf[i] = pld[(size_t)i * kK];                  // prefetch, used next block
            const float nx0 = fmaf(a00, x0, fmaf(a01, x1, b0 * u));
            const float nx1 = fmaf(a10, x0, fmaf(a11, x1, b1 * u));
            x0 = nx0; x1 = nx1;
            pst[(size_t)i * kK] = nx1;
        }
    }
    // Epilogue: last P steps, no prefetch.
    {
        float* __restrict__ pst = pout + (size_t)(kT - kP) * kK;
        #pragma unroll
        for (int i = 0; i < kP; ++i) {
            const float u = buf[i];
            const float nx0 = fmaf(a00, x0, fmaf(a01, x1, b0 * u));
            const float nx1 = fmaf(a10, x0, fmaf(a11, x1, b1 * u));
            x0 = nx0; x1 = nx1;
            pst[(size_t)i * kK] = nx1;
        }
    }
}

extern "C" void kernel_launch(void* const* d_in, const int* in_sizes, int n_in,
                              void* d_out, int out_size, void* d_ws, size_t ws_size,
                              hipStream_t stream) {
    const float* in  = (const float*)d_in[0];   // [64,1024,512] fp32
    const float* il  = (const float*)d_in[1];   // [512] fp32
    const float* tau = (const float*)d_in[2];   // [512] fp32
    float* out = (float*)d_out;                 // [64,1024,512] fp32

    const int total = kB * kK;                  // 32768 chains
    dim3 block(64);
    dim3 grid(total / 64);                      // 512 blocks -> 2 per CU
    alpha_scan<<<grid, block, 0, stream>>>(in, il, tau, out);
}